// Round 14
// baseline (221.786 us; speedup 1.0000x reference)
//
#include <hip/hip_runtime.h>
#include <stdint.h>

#define NTOK 4096
#define DD 1024
#define HH 2048
#define NE 8
#define CAP 4096

typedef short bf16x8 __attribute__((ext_vector_type(8)));
typedef float f32x4 __attribute__((ext_vector_type(4)));
typedef unsigned short u16;
typedef unsigned int u32;

__device__ __forceinline__ u16 f2b(float f){
    union { float f; u32 u; } v; v.f = f;
    return (u16)((v.u + 0x7fffu + ((v.u >> 16) & 1u)) >> 16);
}
__device__ __forceinline__ float b2f(u16 h){
    union { u32 u; float f; } v; v.u = ((u32)h) << 16;
    return v.f;
}
__device__ __forceinline__ u32 pk2(float a, float b){
    return (u32)f2b(a) | ((u32)f2b(b) << 16);
}
// async global->LDS, 16B per lane; LDS dest = wave-uniform base + lane*16
__device__ __forceinline__ void gload16(const u16* g, u16* l){
    __builtin_amdgcn_global_load_lds((const __attribute__((address_space(1))) u32*)g,
                                     (__attribute__((address_space(3))) u32*)l, 16, 0, 0);
}
// inline prefix: offs[e] = sum cnt[0..e)
__device__ __forceinline__ int prefix_off(const int* __restrict__ cnt, int e){
    int o = 0;
    #pragma unroll
    for (int i = 0; i < NE; ++i) if (i < e) o += cnt[i];
    return o;
}

// ---------------- prep: router (first 256 blocks) || W1/W3 cvt (rest) ----------------
__global__ __launch_bounds__(256) void prep_kernel(const float* __restrict__ x,
        const float* __restrict__ Wr,
        const float* __restrict__ W1, const float* __restrict__ W3,
        u16* __restrict__ xb, u16* __restrict__ w1b, u16* __restrict__ w3b,
        int* __restrict__ cnt, int* __restrict__ list,
        float* __restrict__ glist, float* __restrict__ psum,
        int* __restrict__ cnt1, int* __restrict__ islot){
    __shared__ float wS[NE * DD];
    __shared__ float psumS[NE];
    __shared__ int cnt1S[NE], cntS[NE], baseS[NE];
    __shared__ int tE[32], tL[32];
    __shared__ float tP[32];
    int tid = threadIdx.x;
    int bid = blockIdx.x;

    if (bid >= 256){
        int cb = bid - 256;                     // 0..2047
        int m = cb >> 10, blk = cb & 1023;
        const float* s = (m == 0) ? W1 : W3;
        u16* d = (m == 0) ? w1b : w3b;
        int base = blk * 4096 + tid;
        #pragma unroll 4
        for (int j = 0; j < 16; ++j){
            int i = base + j * 256;
            float4 v = reinterpret_cast<const float4*>(s)[i];
            ushort4 o; o.x = f2b(v.x); o.y = f2b(v.y); o.z = f2b(v.z); o.w = f2b(v.w);
            reinterpret_cast<ushort4*>(d)[i] = o;
        }
        return;
    }

    for (int i = tid; i < NE * DD / 4; i += 256)
        reinterpret_cast<float4*>(wS)[i] = reinterpret_cast<const float4*>(Wr)[i];
    if (tid < NE){ psumS[tid] = 0.f; cnt1S[tid] = 0; cntS[tid] = 0; }
    __syncthreads();
    int lane = tid & 63, w = tid >> 6;
    for (int t = 0; t < 4; ++t){
        int li = w * 4 + t;
        int n = bid * 16 + li;
        const float4* xr = reinterpret_cast<const float4*>(x + (size_t)n * DD);
        ushort4* xbr = reinterpret_cast<ushort4*>(xb + (size_t)n * DD);
        float acc[NE];
        #pragma unroll
        for (int e = 0; e < NE; ++e) acc[e] = 0.f;
        #pragma unroll
        for (int j = 0; j < 4; ++j){
            float4 xv = xr[lane + 64 * j];
            ushort4 xo; xo.x = f2b(xv.x); xo.y = f2b(xv.y); xo.z = f2b(xv.z); xo.w = f2b(xv.w);
            xbr[lane + 64 * j] = xo;
            #pragma unroll
            for (int e = 0; e < NE; ++e){
                float4 wv = reinterpret_cast<const float4*>(wS + e * DD)[lane + 64 * j];
                acc[e] += xv.x * wv.x + xv.y * wv.y + xv.z * wv.z + xv.w * wv.w;
            }
        }
        #pragma unroll
        for (int e = 0; e < NE; ++e){
            float v = acc[e];
            #pragma unroll
            for (int s = 32; s > 0; s >>= 1) v += __shfl_xor(v, s);
            acc[e] = v;
        }
        if (lane == 0){
            float mx = acc[0];
            #pragma unroll
            for (int e = 1; e < NE; ++e) mx = fmaxf(mx, acc[e]);
            float p[NE], sm = 0.f;
            #pragma unroll
            for (int e = 0; e < NE; ++e){ p[e] = expf(acc[e] - mx); sm += p[e]; }
            float inv = 1.f / sm;
            #pragma unroll
            for (int e = 0; e < NE; ++e){ p[e] *= inv; atomicAdd(&psumS[e], p[e]); }
            int i0 = 0;
            #pragma unroll
            for (int e = 1; e < NE; ++e) if (acc[e] > acc[i0]) i0 = e;
            int i1 = -1;
            #pragma unroll
            for (int e = 0; e < NE; ++e) if (e != i0 && (i1 < 0 || acc[e] > acc[i1])) i1 = e;
            atomicAdd(&cnt1S[i0], 1);
            int l0 = atomicAdd(&cntS[i0], 1);
            int l1 = atomicAdd(&cntS[i1], 1);
            tE[li * 2] = i0; tE[li * 2 + 1] = i1;
            tP[li * 2] = p[i0]; tP[li * 2 + 1] = p[i1];
            tL[li * 2] = l0; tL[li * 2 + 1] = l1;
        }
    }
    __syncthreads();
    if (tid < NE){
        baseS[tid] = atomicAdd(&cnt[tid], cntS[tid]);
        atomicAdd(&psum[tid], psumS[tid]);
        atomicAdd(&cnt1[tid], cnt1S[tid]);
    }
    __syncthreads();
    if (tid < 32){
        int e = tE[tid], pos = baseS[e] + tL[tid];
        int n = bid * 16 + (tid >> 1);
        list[e * CAP + pos]  = n;
        glist[e * CAP + pos] = tP[tid];
        islot[n * 2 + (tid & 1)] = e * CAP + pos;
    }
}

// ================= ffn1: 256x256x64 8-wave 4-phase dual-GEMM (m201-style) =================
// Blocks 0..511: GEMM (8e x 16n0t x 4 mt-slots). Blocks 512..1535: W2-cvt fillers.
// B-tile rows: br -> matrix=(br>>4)&1 (0=W1,1=W3), col = n0g + (br>>5)*16 + (br&15):
// W1/W3 interleaved at 16-row granularity so SwiGLU pairs are wave-local.
// Per K-step (BK=64), 4 phases of {ds_read quadrant; issue stage; barrier; setprio;
// 16 MFMA; setprio; barrier}. Staging (slab = 8 gload-calls of 8KB): A(t+2) calls {0,2}
// at ph1 (rows freed by ph0), {1,3} at ph3 (freed by ph2); B(t+1) at ph0 into the
// OTHER buffer (not read this step). Single counted vmcnt(4) per step at ph3
// (forces slab t+1 complete, leaves A(t+2)'s 4 in flight). vmcnt(0) only at t=14.
__global__ __launch_bounds__(512, 2) void ffn1_kernel(const u16* __restrict__ xb,
        const u16* __restrict__ w1b, const u16* __restrict__ w3b,
        const float* __restrict__ W2f, u16* __restrict__ w2b,
        const int* __restrict__ cnt, const int* __restrict__ list,
        u16* __restrict__ hbuf){
    int bid = blockIdx.x;                       // 1536 = 512 GEMM + 1024 cvt
    int tid = threadIdx.x;

    if (bid >= 512){
        // -------- W2 conversion filler (512 threads, 8 float4 each) --------
        int cb = bid - 512;                     // 0..1023
        int base = cb * 4096 + tid;
        #pragma unroll 4
        for (int j = 0; j < 8; ++j){
            int i = base + j * 512;
            float4 v = reinterpret_cast<const float4*>(W2f)[i];
            ushort4 o; o.x = f2b(v.x); o.y = f2b(v.y); o.z = f2b(v.z); o.w = f2b(v.w);
            reinterpret_cast<ushort4*>(w2b)[i] = o;
        }
        return;
    }

    __shared__ u16 aS[2 * 256 * 64];            // 64KB dbuf A
    __shared__ u16 bS[2 * 256 * 64];            // 64KB dbuf B

    int e = bid & 7;
    int slot = bid >> 3;                        // 0..63
    int n0t = slot & 15, mtg = slot >> 4;
    int rows = cnt[e];
    int hoff = prefix_off(cnt, e);
    int n0g = n0t * 128;

    int lane = tid & 63, w = tid >> 6;
    int wr = w >> 2, wc = w & 3;                // 2M x 4N waves; per-wave 128M x 64N
    int fr = lane & 15, fg = lane >> 4, fr7 = fr & 7;
    int sr = tid >> 3;                          // staging row within 64-row call
    int ce2 = ((tid & 7) ^ (sr & 7)) * 8;       // XOR-swizzled source col

    // B pointers per 64-row call (const per block)
    const u16* bp[4];
    #pragma unroll
    for (int c = 0; c < 4; ++c){
        int br = c * 64 + sr;
        int which = (br >> 4) & 1;
        int wcol = n0g + (br >> 5) * 16 + (br & 15);
        bp[c] = (which ? w3b : w1b) + ((size_t)e * HH + wcol) * DD + ce2;
    }
    int arow = wr * 128 + fr;
    int brow = wc * 64 + fr;

    for (int mt = mtg; mt < 16; mt += 4){
        int m0 = mt << 8;
        if (m0 >= rows) break;                  // block-uniform

        const u16* ap[4];
        #pragma unroll
        for (int c = 0; c < 4; ++c){
            int r = m0 + c * 64 + sr;
            int tok = list[e * CAP + (r < rows ? r : rows - 1)];
            ap[c] = xb + (size_t)tok * DD + ce2;
        }

        f32x4 acc[8][4];
        #pragma unroll
        for (int mi = 0; mi < 8; ++mi)
            #pragma unroll
            for (int ni = 0; ni < 4; ++ni)
                #pragma unroll
                for (int j = 0; j < 4; ++j) acc[mi][ni][j] = 0.f;

        auto SA = [&](int buf, int c, int k){
            gload16(ap[c] + k, aS + buf * 16384 + c * 4096 + tid * 8);
        };
        auto SB = [&](int buf, int c, int k){
            gload16(bp[c] + k, bS + buf * 16384 + c * 4096 + tid * 8);
        };

        // prologue: slab0 A+B -> buf0; slab1 A -> buf1 (B(1) staged at t=0 ph0)
        #pragma unroll
        for (int c = 0; c < 4; ++c) SA(0, c, 0);
        #pragma unroll
        for (int c = 0; c < 4; ++c) SB(0, c, 0);
        #pragma unroll
        for (int c = 0; c < 4; ++c) SA(1, c, 64);
        asm volatile("s_waitcnt vmcnt(4)" ::: "memory");   // slab0 done; A(1) in flight
        asm volatile("s_barrier" ::: "memory");

        for (int t = 0; t < 16; ++t){
            int cur = t & 1;
            const u16* Ac = aS + cur * 16384;
            const u16* Bc = bS + cur * 16384;
            bf16x8 a[4][2], b[2][2];

            // ---- phase 0: quadrant (mh=0, nh=0) ----
            #pragma unroll
            for (int mi = 0; mi < 4; ++mi)
                #pragma unroll
                for (int ks = 0; ks < 2; ++ks)
                    a[mi][ks] = *(const bf16x8*)&Ac[(arow + mi * 16) * 64 + (((ks * 4 + fg) ^ fr7) * 8)];
            #pragma unroll
            for (int ni = 0; ni < 2; ++ni)
                #pragma unroll
                for (int ks = 0; ks < 2; ++ks)
                    b[ni][ks] = *(const bf16x8*)&Bc[(brow + ni * 16) * 64 + (((ks * 4 + fg) ^ fr7) * 8)];
            if (t + 1 < 16){                    // B(t+1) -> other buffer (not read this step)
                #pragma unroll
                for (int c = 0; c < 4; ++c) SB(cur ^ 1, c, (t + 1) * 64);
            }
            asm volatile("s_barrier" ::: "memory");
            __builtin_amdgcn_s_setprio(1);
            #pragma unroll
            for (int ks = 0; ks < 2; ++ks)
                #pragma unroll
                for (int mi = 0; mi < 4; ++mi)
                    #pragma unroll
                    for (int ni = 0; ni < 2; ++ni)
                        acc[mi][ni] = __builtin_amdgcn_mfma_f32_16x16x32_bf16(a[mi][ks], b[ni][ks], acc[mi][ni], 0, 0, 0);
            __builtin_amdgcn_s_setprio(0);
            asm volatile("s_barrier" ::: "memory");

            // ---- phase 1: (mh=0, nh=1) -- reuse a ----
            #pragma unroll
            for (int ni = 0; ni < 2; ++ni)
                #pragma unroll
                for (int ks = 0; ks < 2; ++ks)
                    b[ni][ks] = *(const bf16x8*)&Bc[(brow + 32 + ni * 16) * 64 + (((ks * 4 + fg) ^ fr7) * 8)];
            if (t + 2 < 16){ SA(cur, 0, (t + 2) * 64); SA(cur, 2, (t + 2) * 64); }  // rows freed by ph0
            asm volatile("s_barrier" ::: "memory");
            __builtin_amdgcn_s_setprio(1);
            #pragma unroll
            for (int ks = 0; ks < 2; ++ks)
                #pragma unroll
                for (int mi = 0; mi < 4; ++mi)
                    #pragma unroll
                    for (int ni = 0; ni < 2; ++ni)
                        acc[mi][2 + ni] = __builtin_amdgcn_mfma_f32_16x16x32_bf16(a[mi][ks], b[ni][ks], acc[mi][2 + ni], 0, 0, 0);
            __builtin_amdgcn_s_setprio(0);
            asm volatile("s_barrier" ::: "memory");

            // ---- phase 2: (mh=1, nh=0) ----
            #pragma unroll
            for (int mi = 0; mi < 4; ++mi)
                #pragma unroll
                for (int ks = 0; ks < 2; ++ks)
                    a[mi][ks] = *(const bf16x8*)&Ac[(arow + 64 + mi * 16) * 64 + (((ks * 4 + fg) ^ fr7) * 8)];
            #pragma unroll
            for (int ni = 0; ni < 2; ++ni)
                #pragma unroll
                for (int ks = 0; ks < 2; ++ks)
                    b[ni][ks] = *(const bf16x8*)&Bc[(brow + ni * 16) * 64 + (((ks * 4 + fg) ^ fr7) * 8)];
            asm volatile("s_barrier" ::: "memory");
            __builtin_amdgcn_s_setprio(1);
            #pragma unroll
            for (int ks = 0; ks < 2; ++ks)
                #pragma unroll
                for (int mi = 0; mi < 4; ++mi)
                    #pragma unroll
                    for (int ni = 0; ni < 2; ++ni)
                        acc[4 + mi][ni] = __builtin_amdgcn_mfma_f32_16x16x32_bf16(a[mi][ks], b[ni][ks], acc[4 + mi][ni], 0, 0, 0);
            __builtin_amdgcn_s_setprio(0);
            asm volatile("s_barrier" ::: "memory");

            // ---- phase 3: (mh=1, nh=1) ----
            #pragma unroll
            for (int ni = 0; ni < 2; ++ni)
                #pragma unroll
                for (int ks = 0; ks < 2; ++ks)
                    b[ni][ks] = *(const bf16x8*)&Bc[(brow + 32 + ni * 16) * 64 + (((ks * 4 + fg) ^ fr7) * 8)];
            if (t + 2 < 16){
                SA(cur, 1, (t + 2) * 64); SA(cur, 3, (t + 2) * 64);   // rows freed by ph2
                asm volatile("s_waitcnt vmcnt(4)" ::: "memory");      // slab t+1 done; A(t+2) in flight
            } else if (t + 1 < 16){
                asm volatile("s_waitcnt vmcnt(0)" ::: "memory");      // tail drain (t=14)
            }
            asm volatile("s_barrier" ::: "memory");
            __builtin_amdgcn_s_setprio(1);
            #pragma unroll
            for (int ks = 0; ks < 2; ++ks)
                #pragma unroll
                for (int mi = 0; mi < 4; ++mi)
                    #pragma unroll
                    for (int ni = 0; ni < 2; ++ni)
                        acc[4 + mi][2 + ni] = __builtin_amdgcn_mfma_f32_16x16x32_bf16(a[mi][ks], b[ni][ks], acc[4 + mi][2 + ni], 0, 0, 0);
            __builtin_amdgcn_s_setprio(0);
            asm volatile("s_barrier" ::: "memory");
        }

        // epilogue: acc[mi][P*2]=v1, acc[mi][P*2+1]=v3 for cols n0g + (wc*2+P)*16 + fr
        #pragma unroll
        for (int mi = 0; mi < 8; ++mi)
            #pragma unroll
            for (int P = 0; P < 2; ++P)
                #pragma unroll
                for (int j = 0; j < 4; ++j){
                    int r = m0 + wr * 128 + mi * 16 + fg * 4 + j;
                    if (r < rows){
                        int col = n0g + (wc * 2 + P) * 16 + fr;
                        float v1 = acc[mi][P * 2][j], v3 = acc[mi][P * 2 + 1][j];
                        float hv = (v1 / (1.f + expf(-v1))) * v3;
                        hbuf[(size_t)(hoff + r) * HH + col] = f2b(hv);
                    }
                }
    }
}

// ================= ffn2: PERSISTENT y = h W2^T -> ybuf (bf16), 128x128, (256,3) =================
__global__ __launch_bounds__(256, 3) void ffn2_kernel(const u16* __restrict__ hbuf,
        const u16* __restrict__ w2b, const int* __restrict__ cnt,
        u16* __restrict__ ybuf){
    int bid = blockIdx.x;                       // 768
    int e = bid & 7;
    int slot = bid >> 3;                        // 0..95
    int rows = cnt[e];
    int hoff = prefix_off(cnt, e);
    int n0 = (slot & 7) * 128;

    __shared__ u16 aS[128 * 64];
    __shared__ u16 bS[128 * 64];

    int tid = threadIdx.x, lane = tid & 63, w = tid >> 6;
    int wm = (w & 1) * 64, wn = (w >> 1) * 64;
    int fr = lane & 15, fg = lane >> 4, fr7 = fr & 7;
    int rc = lane >> 3, ce = ((lane & 7) ^ rc) * 8;

    const u16* bp = w2b + ((size_t)e * DD + n0 + w * 32 + rc) * HH + ce;
    u16* aL = aS + w * 4 * 512;
    u16* bL = bS + w * 4 * 512;

    for (int mt = slot >> 3; mt < 32; mt += 12){
        int m0 = mt << 7;
        if (m0 >= rows) break;

        const u16* aptr[4];
        #pragma unroll
        for (int q = 0; q < 4; ++q){
            int r = m0 + (w * 4 + q) * 8 + rc;
            if (r >= rows) r = rows - 1;
            aptr[q] = hbuf + (size_t)(hoff + r) * HH + ce;
        }

        f32x4 acc[4][4];
        #pragma unroll
        for (int mi = 0; mi < 4; ++mi)
            #pragma unroll
            for (int ni = 0; ni < 4; ++ni)
                #pragma unroll
                for (int j = 0; j < 4; ++j) acc[mi][ni][j] = 0.f;

        for (int k0 = 0; k0 < HH; k0 += 64){
            #pragma unroll
            for (int q = 0; q < 4; ++q){
                gload16(aptr[q] + k0, aL + q * 512);
                gload16(bp + q * 8 * HH + k0, bL + q * 512);
            }
            __syncthreads();
            #pragma unroll
            for (int ks = 0; ks < 2; ++ks){
                int sl = ((ks * 4 + fg) ^ fr7) * 8;
                bf16x8 a[4], b[4];
                #pragma unroll
                for (int mi = 0; mi < 4; ++mi)
                    a[mi] = *reinterpret_cast<const bf16x8*>(&aS[(wm + mi * 16 + fr) * 64 + sl]);
                #pragma unroll
                for (int ni = 0; ni < 4; ++ni)
                    b[ni] = *reinterpret_cast<const bf16x8*>(&bS[(wn + ni * 16 + fr) * 64 + sl]);
                #pragma unroll
                for (int mi = 0; mi < 4; ++mi)
                    #pragma unroll
                    for (int ni = 0; ni < 4; ++ni)
                        acc[mi][ni] = __builtin_amdgcn_mfma_f32_16x16x32_bf16(a[mi], b[ni], acc[mi][ni], 0, 0, 0);
            }
            __syncthreads();
        }

        #pragma unroll
        for (int mi = 0; mi < 4; ++mi)
            #pragma unroll
            for (int ni = 0; ni < 4; ++ni)
                #pragma unroll
                for (int j = 0; j < 4; ++j){
                    int r = wm + mi * 16 + fg * 4 + j;
                    int tr = m0 + r;
                    if (tr < rows){
                        int c = wn + ni * 16 + fr;
                        ybuf[(size_t)(hoff + tr) * DD + n0 + c] = f2b(acc[mi][ni][j]);
                    }
                }
    }
}

// ---------------- fallback 128x128 kernels (fp32 weights inline-convert) ----------------
__global__ __launch_bounds__(256, 2) void ffn1_small(const u16* __restrict__ xb,
        const float* __restrict__ W1f, const float* __restrict__ W3f,
        const int* __restrict__ cnt, const int* __restrict__ list,
        u16* __restrict__ hbuf){
    int bid = blockIdx.x;
    int widx = (bid & 7) * 512 + (bid >> 3);
    int e = widx >> 9, n0t = (widx >> 5) & 15, mt = widx & 31;
    int rows = cnt[e];
    int m0 = mt * 128;
    if (m0 >= rows) return;
    int n0 = n0t * 128;
    int hoff = prefix_off(cnt, e);
    __shared__ u16 aS[128 * 64];
    __shared__ u16 b1S[128 * 64];
    __shared__ u16 b3S[128 * 64];
    int tid = threadIdx.x, lane = tid & 63, w = tid >> 6;
    int wm = (w & 1) * 64, wn = (w >> 1) * 64;
    int fr = lane & 15, fg = lane >> 4, fr7 = fr & 7;
    int rc = lane >> 3, ce = ((lane & 7) ^ rc) * 8;
    const u16* aptr[4];
    #pragma unroll
    for (int q = 0; q < 4; ++q){
        int r = m0 + (w * 4 + q) * 8 + rc;
        int tok = list[e * CAP + (r < rows ? r : rows - 1)];
        aptr[q] = xb + (size_t)tok * DD + ce;
    }
    size_t brw = (size_t)(e * HH + n0 + w * 32 + rc) * DD + ce;
    const float* b1pf = W1f + brw;
    const float* b3pf = W3f + brw;
    u16* aL  = aS  + w * 4 * 512;
    u16* b1L = b1S + w * 4 * 512;
    u16* b3L = b3S + w * 4 * 512;
    f32x4 acc1[4][4], acc3[4][4];
    #pragma unroll
    for (int mi = 0; mi < 4; ++mi)
        #pragma unroll
        for (int ni = 0; ni < 4; ++ni)
            #pragma unroll
            for (int j = 0; j < 4; ++j){ acc1[mi][ni][j] = 0.f; acc3[mi][ni][j] = 0.f; }
    for (int k0 = 0; k0 < DD; k0 += 64){
        #pragma unroll
        for (int q = 0; q < 4; ++q){
            gload16(aptr[q] + k0, aL + q * 512);
            const float* s1 = b1pf + q * 8 * DD + k0;
            float4 f0 = reinterpret_cast<const float4*>(s1)[0];
            float4 f1 = reinterpret_cast<const float4*>(s1)[1];
            int4 v; v.x = pk2(f0.x,f0.y); v.y = pk2(f0.z,f0.w); v.z = pk2(f1.x,f1.y); v.w = pk2(f1.z,f1.w);
            *reinterpret_cast<int4*>(b1L + q * 512 + lane * 8) = v;
            const float* s3 = b3pf + q * 8 * DD + k0;
            float4 g0 = reinterpret_cast<const float4*>(s3)[0];
            float4 g1 = reinterpret_cast<const float4*>(s3)[1];
            int4 u; u.x = pk2(g0.x,g0.y); u.y = pk2(g0.z,g0.w); u.z = pk2(g1.x,g1.y); u.w = pk2(g1.z,g1.w);
            *reinterpret_cast<int4*>(b3L + q * 512 + lane * 8) = u;
        }
        __syncthreads();
        #pragma unroll
        for (int ks = 0; ks < 2; ++ks){
            int sl = ((ks * 4 + fg) ^ fr7) * 8;
            bf16x8 a[4], b1[4], b3[4];
            #pragma unroll
            for (int mi = 0; mi < 4; ++mi)
                a[mi] = *reinterpret_cast<const bf16x8*>(&aS[(wm + mi * 16 + fr) * 64 + sl]);
            #pragma unroll
            for (int ni = 0; ni < 4; ++ni){
                b1[ni] = *reinterpret_cast<const bf16x8*>(&b1S[(wn + ni * 16 + fr) * 64 + sl]);
                b3[ni] = *reinterpret_cast<const bf16x8*>(&b3S[(wn + ni * 16 + fr) * 64 + sl]);
            }
            #pragma unroll
            for (int mi = 0; mi < 4; ++mi)
                #pragma unroll
                for (int ni = 0; ni < 4; ++ni){
                    acc1[mi][ni] = __builtin_amdgcn_mfma_f32_16x16x32_bf16(a[mi], b1[ni], acc1[mi][ni], 0, 0, 0);
                    acc3[mi][ni] = __builtin_amdgcn_mfma_f32_16x16x32_bf16(a[mi], b3[ni], acc3[mi][ni], 0, 0, 0);
                }
        }
        __syncthreads();
    }
    #pragma unroll
    for (int mi = 0; mi < 4; ++mi)
        #pragma unroll
        for (int ni = 0; ni < 4; ++ni)
            #pragma unroll
            for (int j = 0; j < 4; ++j){
                int r = wm + mi * 16 + fg * 4 + j;
                int tr = m0 + r;
                if (tr < rows){
                    int c = wn + ni * 16 + fr;
                    float v1 = acc1[mi][ni][j], v3 = acc3[mi][ni][j];
                    float hv = (v1 / (1.f + expf(-v1))) * v3;
                    hbuf[(size_t)(hoff + tr) * HH + n0 + c] = f2b(hv);
                }
            }
}

__global__ __launch_bounds__(256, 2) void ffn2_small(const u16* __restrict__ hbuf,
        const float* __restrict__ W2f, const int* __restrict__ cnt,
        u16* __restrict__ ybuf){
    int bid = blockIdx.x;
    int widx = (bid & 7) * 256 + (bid >> 3);
    int e = widx >> 8, n0t = (widx >> 5) & 7, mt = widx & 31;
    int rows = cnt[e];
    int m0 = mt * 128;
    if (m0 >= rows) return;
    int n0 = n0t * 128;
    int hoff = prefix_off(cnt, e);
    __shared__ u16 aS[128 * 64];
    __shared__ u16 bS[128 * 64];
    int tid = threadIdx.x, lane = tid & 63, w = tid >> 6;
    int wm = (w & 1) * 64, wn = (w >> 1) * 64;
    int fr = lane & 15, fg = lane >> 4, fr7 = fr & 7;
    int rc = lane >> 3, ce = ((lane & 7) ^ rc) * 8;
    const u16* aptr[4];
    #pragma unroll
    for (int q = 0; q < 4; ++q){
        int r = m0 + (w * 4 + q) * 8 + rc;
        if (r >= rows) r = rows - 1;
        aptr[q] = hbuf + (size_t)(hoff + r) * HH + ce;
    }
    const float* b2pf = W2f + (size_t)(e * DD + n0 + w * 32 + rc) * HH + ce;
    u16* aL = aS + w * 4 * 512;
    u16* bL = bS + w * 4 * 512;
    f32x4 acc[4][4];
    #pragma unroll
    for (int mi = 0; mi < 4; ++mi)
        #pragma unroll
        for (int ni = 0; ni < 4; ++ni)
            #pragma unroll
            for (int j = 0; j < 4; ++j) acc[mi][ni][j] = 0.f;
    for (int k0 = 0; k0 < HH; k0 += 64){
        #pragma unroll
        for (int q = 0; q < 4; ++q){
            gload16(aptr[q] + k0, aL + q * 512);
            const float* s2 = b2pf + q * 8 * HH + k0;
            float4 f0 = reinterpret_cast<const float4*>(s2)[0];
            float4 f1 = reinterpret_cast<const float4*>(s2)[1];
            int4 v; v.x = pk2(f0.x,f0.y); v.y = pk2(f0.z,f0.w); v.z = pk2(f1.x,f1.y); v.w = pk2(f1.z,f1.w);
            *reinterpret_cast<int4*>(bL + q * 512 + lane * 8) = v;
        }
        __syncthreads();
        #pragma unroll
        for (int ks = 0; ks < 2; ++ks){
            int sl = ((ks * 4 + fg) ^ fr7) * 8;
            bf16x8 a[4], b[4];
            #pragma unroll
            for (int mi = 0; mi < 4; ++mi)
                a[mi] = *reinterpret_cast<const bf16x8*>(&aS[(wm + mi * 16 + fr) * 64 + sl]);
            #pragma unroll
            for (int ni = 0; ni < 4; ++ni)
                b[ni] = *reinterpret_cast<const bf16x8*>(&bS[(wn + ni * 16 + fr) * 64 + sl]);
            #pragma unroll
            for (int mi = 0; mi < 4; ++mi)
                #pragma unroll
                for (int ni = 0; ni < 4; ++ni)
                    acc[mi][ni] = __builtin_amdgcn_mfma_f32_16x16x32_bf16(a[mi], b[ni], acc[mi][ni], 0, 0, 0);
        }
        __syncthreads();
    }
    #pragma unroll
    for (int mi = 0; mi < 4; ++mi)
        #pragma unroll
        for (int ni = 0; ni < 4; ++ni)
            #pragma unroll
            for (int j = 0; j < 4; ++j){
                int r = wm + mi * 16 + fg * 4 + j;
                int tr = m0 + r;
                if (tr < rows){
                    int c = wn + ni * 16 + fr;
                    ybuf[(size_t)(hoff + tr) * DD + n0 + c] = f2b(acc[mi][ni][j]);
                }
            }
}

// ---------------- combine: out[n] = g0*ybuf[slot0] + g1*ybuf[slot1]; thread 0 adds aux ----------------
__global__ __launch_bounds__(256) void combine_kernel(const u16* __restrict__ ybuf,
        const int* __restrict__ islot, const int* __restrict__ cnt,
        const float* __restrict__ glist, const float* __restrict__ psum,
        const int* __restrict__ cnt1, float* __restrict__ out){
    int idx = blockIdx.x * 256 + threadIdx.x;
    if (idx == 0){
        float aux = 0.f;
        #pragma unroll
        for (int e = 0; e < NE; ++e)
            aux += ((float)cnt1[e] * (1.f / NTOK)) * (psum[e] * (1.f / NTOK));
        out[(size_t)NTOK * DD] = 0.01f * aux * (float)NE;
    }
    int n = idx >> 7, c = (idx & 127) * 8;
    int id0 = islot[n * 2], id1 = islot[n * 2 + 1];
    int r0 = prefix_off(cnt, id0 >> 12) + (id0 & 4095);
    int r1 = prefix_off(cnt, id1 >> 12) + (id1 & 4095);
    float g0 = glist[id0], g1 = glist[id1];
    ushort4 y0a = reinterpret_cast<const ushort4*>(ybuf + (size_t)r0 * DD + c)[0];
    ushort4 y0b = reinterpret_cast<const ushort4*>(ybuf + (size_t)r0 * DD + c)[1];
    ushort4 y1a = reinterpret_cast<const ushort4*>(ybuf + (size_t)r1 * DD + c)[0];
    ushort4 y1b = reinterpret_cast<const ushort4*>(ybuf + (size_t)r1 * DD + c)[1];
    float4 o0, o1;
    o0.x = g0 * b2f(y0a.x) + g1 * b2f(y1a.x);
    o0.y = g0 * b2f(y0a.y) + g1 * b2f(y1a.y);
    o0.z = g0 * b2f(y0a.z) + g1 * b2f(y1a.z);
    o0.w = g0 * b2f(y0a.w) + g1 * b2f(y1a.w);
    o1.x = g0 * b2f(y0b.x) + g1 * b2f(y1b.x);
    o1.y = g0 * b2f(y0b.y) + g1 * b2f(y1b.y);
    o1.z = g0 * b2f(y0b.z) + g1 * b2f(y1b.z);
    o1.w = g0 * b2f(y0b.w) + g1 * b2f(y1b.w);
    float4* op = reinterpret_cast<float4*>(out + (size_t)n * DD + c);
    op[0] = o0; op[1] = o1;
}

// ---------------- launch ----------------
// ws layout unchanged from R12.  NEED_FULL = 142,901,504 B
extern "C" void kernel_launch(void* const* d_in, const int* in_sizes, int n_in,
                              void* d_out, int out_size, void* d_ws, size_t ws_size,
                              hipStream_t stream) {
    const float* x  = (const float*)d_in[0];
    const float* Wr = (const float*)d_in[1];
    const float* W1 = (const float*)d_in[2];
    const float* W2 = (const float*)d_in[3];
    const float* W3 = (const float*)d_in[4];
    float* out = (float*)d_out;

    char* wp = (char*)d_ws;
    u16*   hbuf  = (u16*)  (wp);
    u16*   xb    = (u16*)  (wp + 33554432);
    int*   list  = (int*)  (wp + 41943040);
    float* glist = (float*)(wp + 42074112);
    int*   cnt   = (int*)  (wp + 42205184);
    float* psum  = (float*)(wp + 42205216);
    int*   cnt1  = (int*)  (wp + 42205248);
    int*   islot = (int*)  (wp + 42205312);
    const size_t WOFF = 42238208;
    const size_t WB   = 33554432;
    u16* w1b = (u16*)(wp + WOFF);
    u16* w2b = (u16*)(wp + WOFF + WB);
    u16* w3b = (u16*)(wp + WOFF + 2 * WB);
    u16* ybuf = (u16*)(wp + WOFF);               // overlays w1b (dead after ffn1)
    const size_t NEED_FULL = WOFF + 3 * WB;
    bool bw = ws_size >= NEED_FULL;

    hipMemsetAsync(wp + 42205184, 0, 128, stream);

    prep_kernel<<<bw ? 2304 : 256, 256, 0, stream>>>(
        x, Wr, W1, W3, xb, w1b, w3b, cnt, list, glist, psum, cnt1, islot);
    if (bw){
        // ffn1 256^2 8-wave 4-phase GEMM (0..511) + W2 convert filler (512..1535)
        ffn1_kernel<<<1536, 512, 0, stream>>>(xb, w1b, w3b, W2, w2b, cnt, list, hbuf);
        ffn2_kernel<<<768, 256, 0, stream>>>(hbuf, w2b, cnt, ybuf);
    } else {
        ffn1_small<<<4096, 256, 0, stream>>>(xb, W1, W3, cnt, list, hbuf);
        ffn2_small<<<2048, 256, 0, stream>>>(hbuf, W2, cnt, ybuf);
    }
    combine_kernel<<<NTOK * (DD / 8) / 256, 256, 0, stream>>>(
        ybuf, islot, cnt, glist, psum, cnt1, out);
}

// Round 15
// 196.384 us; speedup vs baseline: 1.1293x; 1.1293x over previous
//
#include <hip/hip_runtime.h>
#include <stdint.h>

#define NTOK 4096
#define DD 1024
#define HH 2048
#define NE 8
#define CAP 4096

typedef short bf16x8 __attribute__((ext_vector_type(8)));
typedef float f32x4 __attribute__((ext_vector_type(4)));
typedef unsigned short u16;
typedef unsigned int u32;

__device__ __forceinline__ u16 f2b(float f){
    union { float f; u32 u; } v; v.f = f;
    return (u16)((v.u + 0x7fffu + ((v.u >> 16) & 1u)) >> 16);
}
__device__ __forceinline__ float b2f(u16 h){
    union { u32 u; float f; } v; v.u = ((u32)h) << 16;
    return v.f;
}
__device__ __forceinline__ u32 pk2(float a, float b){
    return (u32)f2b(a) | ((u32)f2b(b) << 16);
}
// async global->LDS, 16B per lane; LDS dest = wave-uniform base + lane*16
__device__ __forceinline__ void gload16(const u16* g, u16* l){
    __builtin_amdgcn_global_load_lds((const __attribute__((address_space(1))) u32*)g,
                                     (__attribute__((address_space(3))) u32*)l, 16, 0, 0);
}
// inline prefix: offs[e] = sum cnt[0..e)
__device__ __forceinline__ int prefix_off(const int* __restrict__ cnt, int e){
    int o = 0;
    #pragma unroll
    for (int i = 0; i < NE; ++i) if (i < e) o += cnt[i];
    return o;
}

// ---------------- prep: router (first 256 blocks) || W1/W3 cvt (rest) ----------------
// W2 conversion moved into ffn1's dispatch (filler blocks) -- ffn1 doesn't read w2b.
__global__ __launch_bounds__(256) void prep_kernel(const float* __restrict__ x,
        const float* __restrict__ Wr,
        const float* __restrict__ W1, const float* __restrict__ W3,
        u16* __restrict__ xb, u16* __restrict__ w1b, u16* __restrict__ w3b,
        int* __restrict__ cnt, int* __restrict__ list,
        float* __restrict__ glist, float* __restrict__ psum,
        int* __restrict__ cnt1, int* __restrict__ islot){
    __shared__ float wS[NE * DD];
    __shared__ float psumS[NE];
    __shared__ int cnt1S[NE], cntS[NE], baseS[NE];
    __shared__ int tE[32], tL[32];
    __shared__ float tP[32];
    int tid = threadIdx.x;
    int bid = blockIdx.x;

    if (bid >= 256){
        // -------- W1/W3 conversion: 16 float4 per thread --------
        int cb = bid - 256;                     // 0..2047
        int m = cb >> 10, blk = cb & 1023;
        const float* s = (m == 0) ? W1 : W3;
        u16* d = (m == 0) ? w1b : w3b;
        int base = blk * 4096 + tid;            // float4 index
        #pragma unroll 4
        for (int j = 0; j < 16; ++j){
            int i = base + j * 256;
            float4 v = reinterpret_cast<const float4*>(s)[i];
            ushort4 o; o.x = f2b(v.x); o.y = f2b(v.y); o.z = f2b(v.z); o.w = f2b(v.w);
            reinterpret_cast<ushort4*>(d)[i] = o;
        }
        return;
    }

    // -------- router path (block-aggregated atomics) + x->bf16 fused --------
    for (int i = tid; i < NE * DD / 4; i += 256)
        reinterpret_cast<float4*>(wS)[i] = reinterpret_cast<const float4*>(Wr)[i];
    if (tid < NE){ psumS[tid] = 0.f; cnt1S[tid] = 0; cntS[tid] = 0; }
    __syncthreads();
    int lane = tid & 63, w = tid >> 6;
    for (int t = 0; t < 4; ++t){
        int li = w * 4 + t;
        int n = bid * 16 + li;
        const float4* xr = reinterpret_cast<const float4*>(x + (size_t)n * DD);
        ushort4* xbr = reinterpret_cast<ushort4*>(xb + (size_t)n * DD);
        float acc[NE];
        #pragma unroll
        for (int e = 0; e < NE; ++e) acc[e] = 0.f;
        #pragma unroll
        for (int j = 0; j < 4; ++j){
            float4 xv = xr[lane + 64 * j];
            ushort4 xo; xo.x = f2b(xv.x); xo.y = f2b(xv.y); xo.z = f2b(xv.z); xo.w = f2b(xv.w);
            xbr[lane + 64 * j] = xo;
            #pragma unroll
            for (int e = 0; e < NE; ++e){
                float4 wv = reinterpret_cast<const float4*>(wS + e * DD)[lane + 64 * j];
                acc[e] += xv.x * wv.x + xv.y * wv.y + xv.z * wv.z + xv.w * wv.w;
            }
        }
        #pragma unroll
        for (int e = 0; e < NE; ++e){
            float v = acc[e];
            #pragma unroll
            for (int s = 32; s > 0; s >>= 1) v += __shfl_xor(v, s);
            acc[e] = v;
        }
        if (lane == 0){
            float mx = acc[0];
            #pragma unroll
            for (int e = 1; e < NE; ++e) mx = fmaxf(mx, acc[e]);
            float p[NE], sm = 0.f;
            #pragma unroll
            for (int e = 0; e < NE; ++e){ p[e] = expf(acc[e] - mx); sm += p[e]; }
            float inv = 1.f / sm;
            #pragma unroll
            for (int e = 0; e < NE; ++e){ p[e] *= inv; atomicAdd(&psumS[e], p[e]); }
            int i0 = 0;
            #pragma unroll
            for (int e = 1; e < NE; ++e) if (acc[e] > acc[i0]) i0 = e;
            int i1 = -1;
            #pragma unroll
            for (int e = 0; e < NE; ++e) if (e != i0 && (i1 < 0 || acc[e] > acc[i1])) i1 = e;
            atomicAdd(&cnt1S[i0], 1);
            int l0 = atomicAdd(&cntS[i0], 1);
            int l1 = atomicAdd(&cntS[i1], 1);
            tE[li * 2] = i0; tE[li * 2 + 1] = i1;
            tP[li * 2] = p[i0]; tP[li * 2 + 1] = p[i1];
            tL[li * 2] = l0; tL[li * 2 + 1] = l1;
        }
    }
    __syncthreads();
    if (tid < NE){
        baseS[tid] = atomicAdd(&cnt[tid], cntS[tid]);
        atomicAdd(&psum[tid], psumS[tid]);
        atomicAdd(&cnt1[tid], cnt1S[tid]);
    }
    __syncthreads();
    if (tid < 32){
        int e = tE[tid], pos = baseS[e] + tL[tid];
        int n = bid * 16 + (tid >> 1);
        list[e * CAP + pos]  = n;
        glist[e * CAP + pos] = tP[tid];
        islot[n * 2 + (tid & 1)] = e * CAP + pos;
    }
}

// ================= ffn1: PERSISTENT dual-GEMM (blocks 0..767) + W2 cvt filler (768..1791) =================
// GEMM blocks dispatch first, filling all 3/CU slots; W2-cvt blocks backfill ffn1's
// imbalance tail (2-3 tiles/block). ffn1 has ~4 TB/s BW headroom -> contention minor.
// Stream order guarantees w2b complete before ffn2 launches.
__global__ __launch_bounds__(256, 3) void ffn1_kernel(const u16* __restrict__ xb,
        const u16* __restrict__ w1b, const u16* __restrict__ w3b,
        const float* __restrict__ W2f, u16* __restrict__ w2b,
        const int* __restrict__ cnt, const int* __restrict__ list,
        u16* __restrict__ hbuf){
    int bid = blockIdx.x;                       // 1792 = 768 GEMM + 1024 cvt
    int tid = threadIdx.x;

    if (bid >= 768){
        // -------- W2 conversion filler: 16 float4 per thread --------
        int cb = bid - 768;                     // 0..1023
        int base = cb * 4096 + tid;
        #pragma unroll 4
        for (int j = 0; j < 16; ++j){
            int i = base + j * 256;
            float4 v = reinterpret_cast<const float4*>(W2f)[i];
            ushort4 o; o.x = f2b(v.x); o.y = f2b(v.y); o.z = f2b(v.z); o.w = f2b(v.w);
            reinterpret_cast<ushort4*>(w2b)[i] = o;
        }
        return;
    }

    int e = bid & 7;
    int slot = bid >> 3;                        // 0..95
    int rows = cnt[e];
    int hoff = prefix_off(cnt, e);
    int n0 = (slot & 31) * 64;

    __shared__ u16 aS[128 * 64];
    __shared__ u16 bS[128 * 64];                // rows 0..63: W1[n0..n0+63]; 64..127: W3

    int lane = tid & 63, w = tid >> 6;
    int wm = (w & 1) * 64, wn = (w >> 1) * 32;
    int fr = lane & 15, fg = lane >> 4, fr7 = fr & 7;
    int rc = lane >> 3, ce = ((lane & 7) ^ rc) * 8;

    // hoisted B pointers (n0 const per block)
    const u16* bptr[4];
    #pragma unroll
    for (int q = 0; q < 4; ++q){
        int br = (w * 4 + q) * 8 + rc;          // 0..127
        const u16* wb = (br < 64) ? w1b : w3b;  // wave-uniform
        bptr[q] = wb + ((size_t)e * HH + n0 + (br & 63)) * DD + ce;
    }
    u16* aL = aS + w * 4 * 512;
    u16* bL = bS + w * 4 * 512;

    for (int mt = slot >> 5; mt < 32; mt += 3){
        int m0 = mt << 7;
        if (m0 >= rows) break;                  // mt increasing; block-uniform

        const u16* aptr[4];
        #pragma unroll
        for (int q = 0; q < 4; ++q){
            int r = m0 + (w * 4 + q) * 8 + rc;
            int tok = list[e * CAP + (r < rows ? r : rows - 1)];
            aptr[q] = xb + (size_t)tok * DD + ce;
        }

        f32x4 acc1[4][2], acc3[4][2];
        #pragma unroll
        for (int mi = 0; mi < 4; ++mi)
            #pragma unroll
            for (int ni = 0; ni < 2; ++ni)
                #pragma unroll
                for (int j = 0; j < 4; ++j){ acc1[mi][ni][j] = 0.f; acc3[mi][ni][j] = 0.f; }

        for (int k0 = 0; k0 < DD; k0 += 64){
            #pragma unroll
            for (int q = 0; q < 4; ++q){
                gload16(aptr[q] + k0, aL + q * 512);
                gload16(bptr[q] + k0, bL + q * 512);
            }
            __syncthreads();
            #pragma unroll
            for (int ks = 0; ks < 2; ++ks){
                int sl = ((ks * 4 + fg) ^ fr7) * 8;
                bf16x8 a[4], b1[2], b3[2];
                #pragma unroll
                for (int mi = 0; mi < 4; ++mi)
                    a[mi] = *reinterpret_cast<const bf16x8*>(&aS[(wm + mi * 16 + fr) * 64 + sl]);
                #pragma unroll
                for (int ni = 0; ni < 2; ++ni){
                    b1[ni] = *reinterpret_cast<const bf16x8*>(&bS[(wn + ni * 16 + fr) * 64 + sl]);
                    b3[ni] = *reinterpret_cast<const bf16x8*>(&bS[(64 + wn + ni * 16 + fr) * 64 + sl]);
                }
                #pragma unroll
                for (int mi = 0; mi < 4; ++mi)
                    #pragma unroll
                    for (int ni = 0; ni < 2; ++ni){
                        acc1[mi][ni] = __builtin_amdgcn_mfma_f32_16x16x32_bf16(a[mi], b1[ni], acc1[mi][ni], 0, 0, 0);
                        acc3[mi][ni] = __builtin_amdgcn_mfma_f32_16x16x32_bf16(a[mi], b3[ni], acc3[mi][ni], 0, 0, 0);
                    }
            }
            __syncthreads();
        }

        #pragma unroll
        for (int mi = 0; mi < 4; ++mi)
            #pragma unroll
            for (int ni = 0; ni < 2; ++ni)
                #pragma unroll
                for (int j = 0; j < 4; ++j){
                    int r = wm + mi * 16 + fg * 4 + j;
                    int tr = m0 + r;
                    if (tr < rows){
                        int c = n0 + wn + ni * 16 + fr;
                        float v1 = acc1[mi][ni][j], v3 = acc3[mi][ni][j];
                        float hv = (v1 / (1.f + expf(-v1))) * v3;
                        hbuf[(size_t)(hoff + tr) * HH + c] = f2b(hv);
                    }
                }
    }
}

// ================= ffn2: PERSISTENT y = h W2^T -> ybuf (bf16), 128x128, (256,3) =================
// 768 blocks = 8 experts x 96 slots; n0t = slot&7 const per block -> B hoisted;
// mt = slot>>3, +12, +24 (covers 0..35, bounds-clipped; exact partition).
__global__ __launch_bounds__(256, 3) void ffn2_kernel(const u16* __restrict__ hbuf,
        const u16* __restrict__ w2b, const int* __restrict__ cnt,
        u16* __restrict__ ybuf){
    int bid = blockIdx.x;                       // 768
    int e = bid & 7;
    int slot = bid >> 3;                        // 0..95
    int rows = cnt[e];
    int hoff = prefix_off(cnt, e);
    int n0 = (slot & 7) * 128;

    __shared__ u16 aS[128 * 64];
    __shared__ u16 bS[128 * 64];

    int tid = threadIdx.x, lane = tid & 63, w = tid >> 6;
    int wm = (w & 1) * 64, wn = (w >> 1) * 64;
    int fr = lane & 15, fg = lane >> 4, fr7 = fr & 7;
    int rc = lane >> 3, ce = ((lane & 7) ^ rc) * 8;

    // hoisted B pointer (n0 const per block)
    const u16* bp = w2b + ((size_t)e * DD + n0 + w * 32 + rc) * HH + ce;
    u16* aL = aS + w * 4 * 512;
    u16* bL = bS + w * 4 * 512;

    for (int mt = slot >> 3; mt < 32; mt += 12){
        int m0 = mt << 7;
        if (m0 >= rows) break;

        const u16* aptr[4];
        #pragma unroll
        for (int q = 0; q < 4; ++q){
            int r = m0 + (w * 4 + q) * 8 + rc;
            if (r >= rows) r = rows - 1;
            aptr[q] = hbuf + (size_t)(hoff + r) * HH + ce;
        }

        f32x4 acc[4][4];
        #pragma unroll
        for (int mi = 0; mi < 4; ++mi)
            #pragma unroll
            for (int ni = 0; ni < 4; ++ni)
                #pragma unroll
                for (int j = 0; j < 4; ++j) acc[mi][ni][j] = 0.f;

        for (int k0 = 0; k0 < HH; k0 += 64){
            #pragma unroll
            for (int q = 0; q < 4; ++q){
                gload16(aptr[q] + k0, aL + q * 512);
                gload16(bp + q * 8 * HH + k0, bL + q * 512);
            }
            __syncthreads();
            #pragma unroll
            for (int ks = 0; ks < 2; ++ks){
                int sl = ((ks * 4 + fg) ^ fr7) * 8;
                bf16x8 a[4], b[4];
                #pragma unroll
                for (int mi = 0; mi < 4; ++mi)
                    a[mi] = *reinterpret_cast<const bf16x8*>(&aS[(wm + mi * 16 + fr) * 64 + sl]);
                #pragma unroll
                for (int ni = 0; ni < 4; ++ni)
                    b[ni] = *reinterpret_cast<const bf16x8*>(&bS[(wn + ni * 16 + fr) * 64 + sl]);
                #pragma unroll
                for (int mi = 0; mi < 4; ++mi)
                    #pragma unroll
                    for (int ni = 0; ni < 4; ++ni)
                        acc[mi][ni] = __builtin_amdgcn_mfma_f32_16x16x32_bf16(a[mi], b[ni], acc[mi][ni], 0, 0, 0);
            }
            __syncthreads();
        }

        #pragma unroll
        for (int mi = 0; mi < 4; ++mi)
            #pragma unroll
            for (int ni = 0; ni < 4; ++ni)
                #pragma unroll
                for (int j = 0; j < 4; ++j){
                    int r = wm + mi * 16 + fg * 4 + j;
                    int tr = m0 + r;
                    if (tr < rows){
                        int c = wn + ni * 16 + fr;
                        ybuf[(size_t)(hoff + tr) * DD + n0 + c] = f2b(acc[mi][ni][j]);
                    }
                }
    }
}

// ---------------- fallback 128x128 kernels (fp32 weights inline-convert) ----------------
__global__ __launch_bounds__(256, 2) void ffn1_small(const u16* __restrict__ xb,
        const float* __restrict__ W1f, const float* __restrict__ W3f,
        const int* __restrict__ cnt, const int* __restrict__ list,
        u16* __restrict__ hbuf){
    int bid = blockIdx.x;
    int widx = (bid & 7) * 512 + (bid >> 3);
    int e = widx >> 9, n0t = (widx >> 5) & 15, mt = widx & 31;
    int rows = cnt[e];
    int m0 = mt * 128;
    if (m0 >= rows) return;
    int n0 = n0t * 128;
    int hoff = prefix_off(cnt, e);
    __shared__ u16 aS[128 * 64];
    __shared__ u16 b1S[128 * 64];
    __shared__ u16 b3S[128 * 64];
    int tid = threadIdx.x, lane = tid & 63, w = tid >> 6;
    int wm = (w & 1) * 64, wn = (w >> 1) * 64;
    int fr = lane & 15, fg = lane >> 4, fr7 = fr & 7;
    int rc = lane >> 3, ce = ((lane & 7) ^ rc) * 8;
    const u16* aptr[4];
    #pragma unroll
    for (int q = 0; q < 4; ++q){
        int r = m0 + (w * 4 + q) * 8 + rc;
        int tok = list[e * CAP + (r < rows ? r : rows - 1)];
        aptr[q] = xb + (size_t)tok * DD + ce;
    }
    size_t brw = (size_t)(e * HH + n0 + w * 32 + rc) * DD + ce;
    const float* b1pf = W1f + brw;
    const float* b3pf = W3f + brw;
    u16* aL  = aS  + w * 4 * 512;
    u16* b1L = b1S + w * 4 * 512;
    u16* b3L = b3S + w * 4 * 512;
    f32x4 acc1[4][4], acc3[4][4];
    #pragma unroll
    for (int mi = 0; mi < 4; ++mi)
        #pragma unroll
        for (int ni = 0; ni < 4; ++ni)
            #pragma unroll
            for (int j = 0; j < 4; ++j){ acc1[mi][ni][j] = 0.f; acc3[mi][ni][j] = 0.f; }
    for (int k0 = 0; k0 < DD; k0 += 64){
        #pragma unroll
        for (int q = 0; q < 4; ++q){
            gload16(aptr[q] + k0, aL + q * 512);
            const float* s1 = b1pf + q * 8 * DD + k0;
            float4 f0 = reinterpret_cast<const float4*>(s1)[0];
            float4 f1 = reinterpret_cast<const float4*>(s1)[1];
            int4 v; v.x = pk2(f0.x,f0.y); v.y = pk2(f0.z,f0.w); v.z = pk2(f1.x,f1.y); v.w = pk2(f1.z,f1.w);
            *reinterpret_cast<int4*>(b1L + q * 512 + lane * 8) = v;
            const float* s3 = b3pf + q * 8 * DD + k0;
            float4 g0 = reinterpret_cast<const float4*>(s3)[0];
            float4 g1 = reinterpret_cast<const float4*>(s3)[1];
            int4 u; u.x = pk2(g0.x,g0.y); u.y = pk2(g0.z,g0.w); u.z = pk2(g1.x,g1.y); u.w = pk2(g1.z,g1.w);
            *reinterpret_cast<int4*>(b3L + q * 512 + lane * 8) = u;
        }
        __syncthreads();
        #pragma unroll
        for (int ks = 0; ks < 2; ++ks){
            int sl = ((ks * 4 + fg) ^ fr7) * 8;
            bf16x8 a[4], b1[4], b3[4];
            #pragma unroll
            for (int mi = 0; mi < 4; ++mi)
                a[mi] = *reinterpret_cast<const bf16x8*>(&aS[(wm + mi * 16 + fr) * 64 + sl]);
            #pragma unroll
            for (int ni = 0; ni < 4; ++ni){
                b1[ni] = *reinterpret_cast<const bf16x8*>(&b1S[(wn + ni * 16 + fr) * 64 + sl]);
                b3[ni] = *reinterpret_cast<const bf16x8*>(&b3S[(wn + ni * 16 + fr) * 64 + sl]);
            }
            #pragma unroll
            for (int mi = 0; mi < 4; ++mi)
                #pragma unroll
                for (int ni = 0; ni < 4; ++ni){
                    acc1[mi][ni] = __builtin_amdgcn_mfma_f32_16x16x32_bf16(a[mi], b1[ni], acc1[mi][ni], 0, 0, 0);
                    acc3[mi][ni] = __builtin_amdgcn_mfma_f32_16x16x32_bf16(a[mi], b3[ni], acc3[mi][ni], 0, 0, 0);
                }
        }
        __syncthreads();
    }
    #pragma unroll
    for (int mi = 0; mi < 4; ++mi)
        #pragma unroll
        for (int ni = 0; ni < 4; ++ni)
            #pragma unroll
            for (int j = 0; j < 4; ++j){
                int r = wm + mi * 16 + fg * 4 + j;
                int tr = m0 + r;
                if (tr < rows){
                    int c = wn + ni * 16 + fr;
                    float v1 = acc1[mi][ni][j], v3 = acc3[mi][ni][j];
                    float hv = (v1 / (1.f + expf(-v1))) * v3;
                    hbuf[(size_t)(hoff + tr) * HH + n0 + c] = f2b(hv);
                }
            }
}

__global__ __launch_bounds__(256, 2) void ffn2_small(const u16* __restrict__ hbuf,
        const float* __restrict__ W2f, const int* __restrict__ cnt,
        u16* __restrict__ ybuf){
    int bid = blockIdx.x;
    int widx = (bid & 7) * 256 + (bid >> 3);
    int e = widx >> 8, n0t = (widx >> 5) & 7, mt = widx & 31;
    int rows = cnt[e];
    int m0 = mt * 128;
    if (m0 >= rows) return;
    int n0 = n0t * 128;
    int hoff = prefix_off(cnt, e);
    __shared__ u16 aS[128 * 64];
    __shared__ u16 bS[128 * 64];
    int tid = threadIdx.x, lane = tid & 63, w = tid >> 6;
    int wm = (w & 1) * 64, wn = (w >> 1) * 64;
    int fr = lane & 15, fg = lane >> 4, fr7 = fr & 7;
    int rc = lane >> 3, ce = ((lane & 7) ^ rc) * 8;
    const u16* aptr[4];
    #pragma unroll
    for (int q = 0; q < 4; ++q){
        int r = m0 + (w * 4 + q) * 8 + rc;
        if (r >= rows) r = rows - 1;
        aptr[q] = hbuf + (size_t)(hoff + r) * HH + ce;
    }
    const float* b2pf = W2f + (size_t)(e * DD + n0 + w * 32 + rc) * HH + ce;
    u16* aL = aS + w * 4 * 512;
    u16* bL = bS + w * 4 * 512;
    f32x4 acc[4][4];
    #pragma unroll
    for (int mi = 0; mi < 4; ++mi)
        #pragma unroll
        for (int ni = 0; ni < 4; ++ni)
            #pragma unroll
            for (int j = 0; j < 4; ++j) acc[mi][ni][j] = 0.f;
    for (int k0 = 0; k0 < HH; k0 += 64){
        #pragma unroll
        for (int q = 0; q < 4; ++q){
            gload16(aptr[q] + k0, aL + q * 512);
            const float* s2 = b2pf + q * 8 * HH + k0;
            float4 f0 = reinterpret_cast<const float4*>(s2)[0];
            float4 f1 = reinterpret_cast<const float4*>(s2)[1];
            int4 v; v.x = pk2(f0.x,f0.y); v.y = pk2(f0.z,f0.w); v.z = pk2(f1.x,f1.y); v.w = pk2(f1.z,f1.w);
            *reinterpret_cast<int4*>(bL + q * 512 + lane * 8) = v;
        }
        __syncthreads();
        #pragma unroll
        for (int ks = 0; ks < 2; ++ks){
            int sl = ((ks * 4 + fg) ^ fr7) * 8;
            bf16x8 a[4], b[4];
            #pragma unroll
            for (int mi = 0; mi < 4; ++mi)
                a[mi] = *reinterpret_cast<const bf16x8*>(&aS[(wm + mi * 16 + fr) * 64 + sl]);
            #pragma unroll
            for (int ni = 0; ni < 4; ++ni)
                b[ni] = *reinterpret_cast<const bf16x8*>(&bS[(wn + ni * 16 + fr) * 64 + sl]);
            #pragma unroll
            for (int mi = 0; mi < 4; ++mi)
                #pragma unroll
                for (int ni = 0; ni < 4; ++ni)
                    acc[mi][ni] = __builtin_amdgcn_mfma_f32_16x16x32_bf16(a[mi], b[ni], acc[mi][ni], 0, 0, 0);
        }
        __syncthreads();
    }
    #pragma unroll
    for (int mi = 0; mi < 4; ++mi)
        #pragma unroll
        for (int ni = 0; ni < 4; ++ni)
            #pragma unroll
            for (int j = 0; j < 4; ++j){
                int r = wm + mi * 16 + fg * 4 + j;
                int tr = m0 + r;
                if (tr < rows){
                    int c = wn + ni * 16 + fr;
                    ybuf[(size_t)(hoff + tr) * DD + n0 + c] = f2b(acc[mi][ni][j]);
                }
            }
}

// ---------------- combine: out[n] = g0*ybuf[slot0] + g1*ybuf[slot1]; thread 0 adds aux ----------------
__global__ __launch_bounds__(256) void combine_kernel(const u16* __restrict__ ybuf,
        const int* __restrict__ islot, const int* __restrict__ cnt,
        const float* __restrict__ glist, const float* __restrict__ psum,
        const int* __restrict__ cnt1, float* __restrict__ out){
    int idx = blockIdx.x * 256 + threadIdx.x;   // 4096 tokens * 128 (8 cols each)
    if (idx == 0){
        float aux = 0.f;
        #pragma unroll
        for (int e = 0; e < NE; ++e)
            aux += ((float)cnt1[e] * (1.f / NTOK)) * (psum[e] * (1.f / NTOK));
        out[(size_t)NTOK * DD] = 0.01f * aux * (float)NE;
    }
    int n = idx >> 7, c = (idx & 127) * 8;
    int id0 = islot[n * 2], id1 = islot[n * 2 + 1];
    int r0 = prefix_off(cnt, id0 >> 12) + (id0 & 4095);
    int r1 = prefix_off(cnt, id1 >> 12) + (id1 & 4095);
    float g0 = glist[id0], g1 = glist[id1];
    ushort4 y0a = reinterpret_cast<const ushort4*>(ybuf + (size_t)r0 * DD + c)[0];
    ushort4 y0b = reinterpret_cast<const ushort4*>(ybuf + (size_t)r0 * DD + c)[1];
    ushort4 y1a = reinterpret_cast<const ushort4*>(ybuf + (size_t)r1 * DD + c)[0];
    ushort4 y1b = reinterpret_cast<const ushort4*>(ybuf + (size_t)r1 * DD + c)[1];
    float4 o0, o1;
    o0.x = g0 * b2f(y0a.x) + g1 * b2f(y1a.x);
    o0.y = g0 * b2f(y0a.y) + g1 * b2f(y1a.y);
    o0.z = g0 * b2f(y0a.z) + g1 * b2f(y1a.z);
    o0.w = g0 * b2f(y0a.w) + g1 * b2f(y1a.w);
    o1.x = g0 * b2f(y0b.x) + g1 * b2f(y1b.x);
    o1.y = g0 * b2f(y0b.y) + g1 * b2f(y1b.y);
    o1.z = g0 * b2f(y0b.z) + g1 * b2f(y1b.z);
    o1.w = g0 * b2f(y0b.w) + g1 * b2f(y1b.w);
    float4* op = reinterpret_cast<float4*>(out + (size_t)n * DD + c);
    op[0] = o0; op[1] = o1;
}

// ---------------- launch ----------------
// ws layout (bytes):
//   [0,        33554432)  hbuf  : 8192 x 2048 bf16
//   [33554432, 41943040)  xb    : 4096 x 1024 bf16  (written by router)
//   [41943040, 42074112)  list  : 8 x 4096 int
//   [42074112, 42205184)  glist : 8 x 4096 f32
//   [42205184, 42205312)  counters: cnt/psum/cnt1 (+spare)
//   [42205312, 42238080)  islot : 4096 x 2 int
//   [42238208, +32MB)     w1b (bf16) -- ybuf (bf16 8192x1024) overlays after ffn1
//   [+32MB,    +64MB)     w2b (bf16)
//   [+64MB,    +96MB)     w3b (bf16)      NEED_FULL = 142,901,504 B
extern "C" void kernel_launch(void* const* d_in, const int* in_sizes, int n_in,
                              void* d_out, int out_size, void* d_ws, size_t ws_size,
                              hipStream_t stream) {
    const float* x  = (const float*)d_in[0];
    const float* Wr = (const float*)d_in[1];
    const float* W1 = (const float*)d_in[2];
    const float* W2 = (const float*)d_in[3];
    const float* W3 = (const float*)d_in[4];
    float* out = (float*)d_out;

    char* wp = (char*)d_ws;
    u16*   hbuf  = (u16*)  (wp);
    u16*   xb    = (u16*)  (wp + 33554432);
    int*   list  = (int*)  (wp + 41943040);
    float* glist = (float*)(wp + 42074112);
    int*   cnt   = (int*)  (wp + 42205184);
    float* psum  = (float*)(wp + 42205216);
    int*   cnt1  = (int*)  (wp + 42205248);
    int*   islot = (int*)  (wp + 42205312);
    const size_t WOFF = 42238208;
    const size_t WB   = 33554432;
    u16* w1b = (u16*)(wp + WOFF);
    u16* w2b = (u16*)(wp + WOFF + WB);
    u16* w3b = (u16*)(wp + WOFF + 2 * WB);
    u16* ybuf = (u16*)(wp + WOFF);               // overlays w1b (dead after ffn1)
    const size_t NEED_FULL = WOFF + 3 * WB;
    bool bw = ws_size >= NEED_FULL;

    hipMemsetAsync(wp + 42205184, 0, 128, stream);

    // prep: router (blocks 0..255) + W1/W3 converts (blocks 256..2303) overlapped
    prep_kernel<<<bw ? 2304 : 256, 256, 0, stream>>>(
        x, Wr, W1, W3, xb, w1b, w3b, cnt, list, glist, psum, cnt1, islot);
    if (bw){
        // ffn1 GEMM (0..767) + W2 convert filler (768..1791)
        ffn1_kernel<<<1792, 256, 0, stream>>>(xb, w1b, w3b, W2, w2b, cnt, list, hbuf);
        ffn2_kernel<<<768, 256, 0, stream>>>(hbuf, w2b, cnt, ybuf);
    } else {
        ffn1_small<<<4096, 256, 0, stream>>>(xb, W1, W3, cnt, list, hbuf);
        ffn2_small<<<2048, 256, 0, stream>>>(hbuf, W2, cnt, ybuf);
    }
    combine_kernel<<<NTOK * (DD / 8) / 256, 256, 0, stream>>>(
        ybuf, islot, cnt, glist, psum, cnt1, out);
}